// Round 1
// 343.183 us; speedup vs baseline: 1.0496x; 1.0496x over previous
//
#include <hip/hip_runtime.h>

#define H 10
#define T_LEN 2048
#define BATCH 8192

typedef float v2f __attribute__((ext_vector_type(2)));

__device__ __forceinline__ v2f vdup(float s) { v2f r; r.x = s; r.y = s; return r; }
__device__ __forceinline__ v2f vfma2(v2f a, v2f b, v2f c) {
    return __builtin_elementwise_fma(a, b, c);
}

// DPP row_ror:(2K): within each 16-lane row, dst lane i reads src lane (i-2K)&15.
// (Shift/rotate-"right" moves data toward higher lanes, per GCN cross-lane scan idiom.)
#define ROR2K(x, K) __int_as_float(__builtin_amdgcn_update_dpp(                  \
    0, __float_as_int(x), 0x120 + 2 * (K), 0xF, 0xF, true))

// ---------------------------------------------------------------------------
// Kernel 1: Bmat = expm(triu(A,1) - triu(A,1)^T) in fp64, write fp32 to ws.
// Single block, 128 threads. Fixed scaling s=8, 16 Taylor terms, 8 squarings.
// ---------------------------------------------------------------------------
__global__ void expm_kernel(const float* __restrict__ A, float* __restrict__ Bout) {
    __shared__ double S[H][H];
    __shared__ double P[H][H];
    __shared__ double E[H][H];
    const int tid = threadIdx.x;
    const int i = tid / H, j = tid % H;
    if (tid < H * H) {
        double a = 0.0;
        if (i < j) a = (double)A[i * H + j];
        else if (i > j) a = -(double)A[j * H + i];
        a *= (1.0 / 256.0);          // scale by 2^-8
        S[i][j] = a;
        P[i][j] = a;                 // S^1 / 1!
        E[i][j] = (i == j ? 1.0 : 0.0) + a;
    }
    __syncthreads();
    for (int k = 2; k <= 16; ++k) {
        double acc = 0.0;
        if (tid < H * H) {
            for (int m = 0; m < H; ++m) acc += P[i][m] * S[m][j];
            acc *= (1.0 / (double)k);
        }
        __syncthreads();
        if (tid < H * H) { P[i][j] = acc; E[i][j] += acc; }
        __syncthreads();
    }
    for (int rr = 0; rr < 8; ++rr) {
        double acc = 0.0;
        if (tid < H * H) {
            for (int m = 0; m < H; ++m) acc += E[i][m] * E[m][j];
        }
        __syncthreads();
        if (tid < H * H) E[i][j] = acc;
        __syncthreads();
    }
    if (tid < H * H) Bout[i * H + j] = (float)E[i][j];
}

// ---------------------------------------------------------------------------
// Kernel 2: DPP-exchange recurrence. 8 lanes per batch element; each 16-lane
// row holds 2 batches interleaved (even/odd lanes). Lane q (=(lane&15)>>1)
// owns h[2q], h[2q+1] with H padded 10->16 (pad components provably stay 0:
// zero W rows, zero bias, zero B cols => modrelu(0)=0).
//   - h exchange: 14 x v_mov_dpp row_ror (full-rate VALU) -- NO LDS, NO barrier,
//     nothing on the lgkmcnt critical path.
//   - matvec: 16 x v_pk_fma_f32 against rotation-pre-permuted B columns
//     (Brot[k] <-> source pair m=(q-k)&7, so all register indices are static).
//   - x: 16-step register window (8 float4), prefetched one superstep ahead
//     (~1300 cy at ~85 cy/step covers HBM latency).
// ---------------------------------------------------------------------------
__global__ __launch_bounds__(64)
void rnn_kernel(const float* __restrict__ x,
                const float* __restrict__ Bm,
                const float* __restrict__ Win,
                const float* __restrict__ bmod,
                const float* __restrict__ lW,
                const float* __restrict__ lb,
                float* __restrict__ out) {
    const int lane = threadIdx.x;
    const int l16  = lane & 15;
    const int row  = lane >> 4;       // 0..3 (16-lane row within the wave)
    const int par  = l16 & 1;         // which of the row's 2 batches
    const int q    = l16 >> 1;        // 0..7 position within the 8-lane comb
    const int bb   = blockIdx.x * 8 + row * 2 + par;   // 8192 = 1024*8 exact
    const int o0   = 2 * q, o1 = o0 + 1;               // owned components

    // Rotation-matched B columns: rotation k delivers (h[2m], h[2m+1]) of
    // source m=(q-k)&7; Br0[k]/Br1[k] hold B[2m][o0..o1] / B[2m+1][o0..o1].
    v2f Br0[8], Br1[8];
#pragma unroll
    for (int k = 0; k < 8; ++k) {
        const int m = (q - k) & 7;
        const int j0 = 2 * m, j1 = j0 + 1;
        v2f b0 = vdup(0.f), b1 = vdup(0.f);
        if (o0 < H) {
            if (j0 < H) b0.x = Bm[j0 * H + o0];
            if (j1 < H) b1.x = Bm[j1 * H + o0];
        }
        if (o1 < H) {
            if (j0 < H) b0.y = Bm[j0 * H + o1];
            if (j1 < H) b1.y = Bm[j1 * H + o1];
        }
        Br0[k] = b0; Br1[k] = b1;
    }
    v2f w0v = vdup(0.f), w1v = vdup(0.f), bmv = vdup(0.f);
    if (o0 < H) { w0v.x = Win[o0 * 2]; w1v.x = Win[o0 * 2 + 1]; bmv.x = bmod[o0]; }
    if (o1 < H) { w0v.y = Win[o1 * 2]; w1v.y = Win[o1 * 2 + 1]; bmv.y = bmod[o1]; }

    float hx = 0.f, hy = 0.f;

    const float4* __restrict__ xp4 = (const float4*)(x + (size_t)bb * (T_LEN * 2));
    float4 buf[8];
#pragma unroll
    for (int i = 0; i < 8; ++i) buf[i] = xp4[i];

    for (int t0 = 0; t0 < T_LEN; t0 += 16) {
        float4 c[8];
#pragma unroll
        for (int i = 0; i < 8; ++i) c[i] = buf[i];
        if (t0 + 16 < T_LEN) {
            const int base = (t0 + 16) >> 1;
#pragma unroll
            for (int i = 0; i < 8; ++i) buf[i] = xp4[base + i];
        }
        float xs[32];
#pragma unroll
        for (int i = 0; i < 8; ++i) {
            xs[4 * i + 0] = c[i].x; xs[4 * i + 1] = c[i].y;
            xs[4 * i + 2] = c[i].z; xs[4 * i + 3] = c[i].w;
        }

#pragma unroll
        for (int u = 0; u < 16; ++u) {
            const float x0 = xs[2 * u], x1 = xs[2 * u + 1];
            // two independent pk_fma chains (accA, accB) to keep dep depth low
            v2f accA = vfma2(vdup(x1), w1v, vdup(x0) * w0v);
            v2f accB = vdup(hx) * Br0[0];
            accA = vfma2(vdup(hy), Br1[0], accA);
#define DOTK(K) { const float ex_ = ROR2K(hx, K); const float ey_ = ROR2K(hy, K); \
                  accB = vfma2(vdup(ex_), Br0[K], accB);                          \
                  accA = vfma2(vdup(ey_), Br1[K], accA); }
            DOTK(1) DOTK(2) DOTK(3) DOTK(4) DOTK(5) DOTK(6) DOTK(7)
#undef DOTK
            const v2f s = accA + accB;
            const float rx = fmaxf(fabsf(s.x) + bmv.x, 0.f);
            const float ry = fmaxf(fabsf(s.y) + bmv.y, 0.f);
            hx = __builtin_copysignf(rx, s.x);
            hy = __builtin_copysignf(ry, s.y);
        }
    }

    // epilogue: out[bb][o] = lb[o] + sum_j h_j * lW[o][j], same rotation trick
    v2f L0[8], L1[8];
#pragma unroll
    for (int k = 0; k < 8; ++k) {
        const int m = (q - k) & 7;
        const int j0 = 2 * m, j1 = j0 + 1;
        v2f a0 = vdup(0.f), a1 = vdup(0.f);
        if (o0 < H) {
            if (j0 < H) a0.x = lW[o0 * H + j0];
            if (j1 < H) a1.x = lW[o0 * H + j1];
        }
        if (o1 < H) {
            if (j0 < H) a0.y = lW[o1 * H + j0];
            if (j1 < H) a1.y = lW[o1 * H + j1];
        }
        L0[k] = a0; L1[k] = a1;
    }
    v2f accO = vdup(0.f);
    if (o0 < H) accO.x = lb[o0];
    if (o1 < H) accO.y = lb[o1];
    accO = vfma2(vdup(hx), L0[0], accO);
    accO = vfma2(vdup(hy), L1[0], accO);
#define OUTK(K) { const float ex_ = ROR2K(hx, K); const float ey_ = ROR2K(hy, K); \
                  accO = vfma2(vdup(ex_), L0[K], accO);                           \
                  accO = vfma2(vdup(ey_), L1[K], accO); }
    OUTK(1) OUTK(2) OUTK(3) OUTK(4) OUTK(5) OUTK(6) OUTK(7)
#undef OUTK
    if (o0 < H) {
        float2 st; st.x = accO.x; st.y = accO.y;
        *reinterpret_cast<float2*>(out + (size_t)bb * H + o0) = st;
    }
}

extern "C" void kernel_launch(void* const* d_in, const int* in_sizes, int n_in,
                              void* d_out, int out_size, void* d_ws, size_t ws_size,
                              hipStream_t stream) {
    const float* inputs = (const float*)d_in[0];  // [8192, 2048, 2]
    const float* A      = (const float*)d_in[1];  // [10, 10]
    const float* W_in   = (const float*)d_in[2];  // [10, 2]
    const float* b_mod  = (const float*)d_in[3];  // [10]
    const float* lin_W  = (const float*)d_in[4];  // [10, 10]
    const float* lin_b  = (const float*)d_in[5];  // [10]
    float* out = (float*)d_out;                   // [8192, 10]
    float* Bmat = (float*)d_ws;                   // 100 floats scratch

    expm_kernel<<<1, 128, 0, stream>>>(A, Bmat);
    rnn_kernel<<<BATCH / 8, 64, 0, stream>>>(inputs, Bmat, W_in, b_mod,
                                             lin_W, lin_b, out);
}